// Round 5
// baseline (1700.856 us; speedup 1.0000x reference)
//
#include <hip/hip_runtime.h>
#include <hip/hip_bf16.h>

// Sparse-conv DenseNet block via bf16x3-split MFMA (no fp32 MFMA on CDNA4).
//  - d_out [N,256] = x1|x2|x3|x4 at col offsets 0/64/128/192; later convs
//    gather previous features straight from d_out (concat is free).
//  - W[k] staged in LDS split to bf16 hi/lo in EXACT B-fragment lane order
//    WB[h][kk][t][lane][j] -> ds_read_b128 conflict-free by construction.
//  - Wave = 32 map rows/iter (2x 16-row MFMA subtiles). 3-term split product
//    (ah*bh + al*bh + ah*bl), rel err ~2^-17.
//  - A-operand k-slots match B-staging k-slots -> result invariant to HW
//    internal k-numbering; only the (verified, m89/m91) C/D layout matters:
//    col=lane&15, row=(lane>>4)*4+reg.
//  - x pre-split once into bf16 hi/lo ws arrays (kills 40% of hot-loop VALU),
//    gated on ws_size; fallback converts in-loop.
//  - Scatter via f32 global atomics; BN = stats kernel + in-place apply.

typedef __attribute__((ext_vector_type(8))) short bf16x8;
typedef __attribute__((ext_vector_type(4))) float f32x4;

__device__ __forceinline__ unsigned short bfbits(float a) {
    union { __hip_bfloat16 b; unsigned short u; } cv;
    cv.b = __float2bfloat16(a);
    return cv.u;
}
__device__ __forceinline__ float bf2f(unsigned short u) {
    return __uint_as_float((unsigned)u << 16);
}
// split (a,b) -> packed hi bf16x2, lo bf16x2 (a in low half)
__device__ __forceinline__ void split2(float a, float b, unsigned& hi, unsigned& lo) {
    const unsigned short ha = bfbits(a), hb = bfbits(b);
    const float ra = a - bf2f(ha), rb = b - bf2f(hb);
    hi = (unsigned)ha | ((unsigned)hb << 16);
    lo = (unsigned)bfbits(ra) | ((unsigned)bfbits(rb) << 16);
}

#define THREADS 512
#define BPK 18   // 18*27 = 486 blocks <= 512 co-resident slots (2/CU): no straggler

__global__ __launch_bounds__(256) void presplit_x(
    const float* __restrict__ x, unsigned* __restrict__ XH,
    unsigned* __restrict__ XL, int nvec)
{
    for (int v = blockIdx.x * 256 + threadIdx.x; v < nvec; v += gridDim.x * 256) {
        const f32x4 f = ((const f32x4*)x)[v];
        unsigned h0, l0, h1, l1;
        split2(f[0], f[1], h0, l0);
        split2(f[2], f[3], h1, l1);
        XH[v * 2] = h0; XH[v * 2 + 1] = h1;
        XL[v * 2] = l0; XL[v * 2 + 1] = l1;
    }
}

template<int SEGS, bool PSX>
__global__ __launch_bounds__(THREADS, 4) void conv_mfma(
    const float* __restrict__ x,     // [N,64] (used when !PSX)
    const short* __restrict__ XH,    // [N,64] bf16 hi (PSX)
    const short* __restrict__ XL,    // [N,64] bf16 lo (PSX)
    float* out_base,                 // d_out [N,256]: gather prev segs, scatter at col_off
    const float* __restrict__ W,     // [27][SEGS*64][64]
    const int* __restrict__ in_map,  // [27][M]
    const int* __restrict__ out_map, // [27][M]
    int col_off, int M, int chunk)
{
    constexpr int CIN = SEGS * 64;
    constexpr int NKK = CIN / 32;
    // [h][kk][t][lane][j] shorts; per (kk,t): 64 lanes x 16B, lane-ordered.
    __shared__ short WB[2 * NKK * 2048];

    const int k   = blockIdx.y;
    const int tid = threadIdx.x;

    // ---- stage W[k]: read coalesced over o, split hi/lo, write frag-order ----
    {
        const float* Wk = W + (size_t)k * CIN * 64;
        const int o = tid & 63, t = o >> 4, lr = o & 15;
        for (int c2 = (tid >> 6) * 2; c2 < CIN; c2 += 2 * (THREADS / 64)) {
            const float a = Wk[(size_t)c2 * 64 + o];
            const float b = Wk[(size_t)(c2 + 1) * 64 + o];
            unsigned hi, lo;
            split2(a, b, hi, lo);
            const int kk = c2 >> 5, kg = (c2 >> 3) & 3, j0 = c2 & 7;  // j0 even
            const int base = ((kk * 4 + t) * 64 + (kg * 16 + lr)) * 8 + j0;
            *(unsigned*)&WB[base] = hi;
            *(unsigned*)&WB[NKK * 2048 + base] = lo;
        }
    }
    __syncthreads();

    const int wave = tid >> 6, lane = tid & 63;
    const int lrow = lane & 15, kgrp = lane >> 4;
    const int cl   = kgrp * 8;            // per-lane k-offset within 32-chunk
    const int rbeg = blockIdx.x * chunk;
    const int rend = min(rbeg + chunk, M);
    const long kM  = (long)k * M;
    const short* WBl = WB + NKK * 2048;

    for (int r0 = rbeg + wave * 32; r0 < rend; r0 += (THREADS / 64) * 32) {
        f32x4 acc[2][4];
#pragma unroll
        for (int st = 0; st < 2; ++st)
#pragma unroll
            for (int t = 0; t < 4; ++t) acc[st][t] = (f32x4){0.f, 0.f, 0.f, 0.f};

        const int ir0 = in_map[kM + min(r0 + lrow,      rend - 1)];
        const int ir1 = in_map[kM + min(r0 + 16 + lrow, rend - 1)];
        const float* b0 = (const float*)out_base + (size_t)ir0 * 256;
        const float* b1 = (const float*)out_base + (size_t)ir1 * 256;

#pragma unroll 1
        for (int kk = 0; kk < NKK; ++kk) {
            const int s   = kk >> 1;
            const int off = (kk & 1) * 32 + cl;

            union { bf16x8 v; unsigned u[4]; } AH0, AL0, AH1, AL1;
            if (PSX && s == 0) {
                AH0.v = *(const bf16x8*)(XH + (size_t)ir0 * 64 + off);
                AL0.v = *(const bf16x8*)(XL + (size_t)ir0 * 64 + off);
                AH1.v = *(const bf16x8*)(XH + (size_t)ir1 * 64 + off);
                AL1.v = *(const bf16x8*)(XL + (size_t)ir1 * 64 + off);
            } else {
                const float* p0 = (s == 0) ? (x + (size_t)ir0 * 64 + off)
                                           : (b0 + (s - 1) * 64 + off);
                const float* p1 = (s == 0) ? (x + (size_t)ir1 * 64 + off)
                                           : (b1 + (s - 1) * 64 + off);
                {
                    const f32x4 f0 = *(const f32x4*)p0;
                    const f32x4 f1 = *(const f32x4*)(p0 + 4);
                    split2(f0[0], f0[1], AH0.u[0], AL0.u[0]);
                    split2(f0[2], f0[3], AH0.u[1], AL0.u[1]);
                    split2(f1[0], f1[1], AH0.u[2], AL0.u[2]);
                    split2(f1[2], f1[3], AH0.u[3], AL0.u[3]);
                }
                {
                    const f32x4 f0 = *(const f32x4*)p1;
                    const f32x4 f1 = *(const f32x4*)(p1 + 4);
                    split2(f0[0], f0[1], AH1.u[0], AL1.u[0]);
                    split2(f0[2], f0[3], AH1.u[1], AL1.u[1]);
                    split2(f1[0], f1[1], AH1.u[2], AL1.u[2]);
                    split2(f1[2], f1[3], AH1.u[3], AL1.u[3]);
                }
            }

#pragma unroll
            for (int t = 0; t < 4; ++t) {
                const int boff = ((kk * 4 + t) * 64 + lane) * 8;  // conflict-free
                const bf16x8 bh = *(const bf16x8*)&WB[boff];
                const bf16x8 bl = *(const bf16x8*)&WBl[boff];
                acc[0][t] = __builtin_amdgcn_mfma_f32_16x16x32_bf16(AH0.v, bh, acc[0][t], 0, 0, 0);
                acc[1][t] = __builtin_amdgcn_mfma_f32_16x16x32_bf16(AH1.v, bh, acc[1][t], 0, 0, 0);
                acc[0][t] = __builtin_amdgcn_mfma_f32_16x16x32_bf16(AL0.v, bh, acc[0][t], 0, 0, 0);
                acc[1][t] = __builtin_amdgcn_mfma_f32_16x16x32_bf16(AL1.v, bh, acc[1][t], 0, 0, 0);
                acc[0][t] = __builtin_amdgcn_mfma_f32_16x16x32_bf16(AH0.v, bl, acc[0][t], 0, 0, 0);
                acc[1][t] = __builtin_amdgcn_mfma_f32_16x16x32_bf16(AH1.v, bl, acc[1][t], 0, 0, 0);
            }
        }

        // ---- scatter: D row = kgrp*4+reg, col = t*16+lrow (verified layout) ----
        float* outw = out_base + col_off;
#pragma unroll
        for (int st = 0; st < 2; ++st) {
            const int rb = r0 + st * 16 + kgrp * 4;
#pragma unroll
            for (int reg = 0; reg < 4; ++reg) {
                const int rr = rb + reg;
                if (rr < rend) {
                    float* rp = outw + (size_t)out_map[kM + rr] * 256 + lrow;
                    atomicAdd(rp +  0, acc[st][0][reg]);
                    atomicAdd(rp + 16, acc[st][1][reg]);
                    atomicAdd(rp + 32, acc[st][2][reg]);
                    atomicAdd(rp + 48, acc[st][3][reg]);
                }
            }
        }
    }
}

__global__ __launch_bounds__(256) void bn_stats(
    const float* __restrict__ y, int N, float* __restrict__ stats /*[512]*/)
{
    const int c = threadIdx.x;
    float s = 0.f, s2 = 0.f;
    for (int n = blockIdx.x; n < N; n += gridDim.x) {
        const float v = y[(size_t)n * 256 + c];
        s += v;
        s2 += v * v;
    }
    atomicAdd(&stats[c], s);
    atomicAdd(&stats[256 + c], s2);
}

__global__ __launch_bounds__(256) void bn_apply(
    float* __restrict__ y, int N, const float* __restrict__ stats,
    const float* __restrict__ gamma, const float* __restrict__ beta)
{
    const int c = threadIdx.x;
    const float invN = 1.0f / (float)N;
    const float mean = stats[c] * invN;
    const float var  = stats[256 + c] * invN - mean * mean;
    const float scale = (1.0f / sqrtf(var + 1e-5f)) * gamma[c];
    const float shift = beta[c] - mean * scale;
    for (int n = blockIdx.x; n < N; n += gridDim.x) {
        const size_t idx = (size_t)n * 256 + c;
        y[idx] = y[idx] * scale + shift;
    }
}

extern "C" void kernel_launch(void* const* d_in, const int* in_sizes, int n_in,
                              void* d_out, int out_size, void* d_ws, size_t ws_size,
                              hipStream_t stream) {
    const float* x     = (const float*)d_in[0];
    const float* W1    = (const float*)d_in[1];
    const float* W2    = (const float*)d_in[2];
    const float* W3    = (const float*)d_in[3];
    const float* W4    = (const float*)d_in[4];
    const float* gamma = (const float*)d_in[5];
    const float* beta  = (const float*)d_in[6];
    const int* in_map  = (const int*)d_in[7];
    const int* out_map = (const int*)d_in[8];

    const int N = in_sizes[0] / 64;       // 120000
    const int M = in_sizes[7] / 27;       // 60000
    float* out   = (float*)d_out;         // [N,256]
    float* stats = (float*)d_ws;          // 512 floats at ws base

    // ws layout: [0,2KB) stats | [4KB,..) XH [N*64 bf16] | XL [N*64 bf16]
    short* XH = (short*)((char*)d_ws + 4096);
    short* XL = XH + (size_t)N * 64;
    const size_t ws_need = 4096 + (size_t)N * 64 * 2 * 2;
    const bool psx = (ws_size >= ws_need);

    hipMemsetAsync(d_out, 0, (size_t)N * 256 * sizeof(float), stream);
    hipMemsetAsync(d_ws, 0, 2048, stream);

    const int chunk = ((((M + BPK - 1) / BPK) + 31) & ~31);  // 3360
    const int gx = (M + chunk - 1) / chunk;                  // 18
    dim3 blk(THREADS);
    dim3 grid(gx, 27);

    if (psx) {
        presplit_x<<<dim3(1024), dim3(256), 0, stream>>>(x, (unsigned*)XH, (unsigned*)XL, N * 16);
        conv_mfma<1, true><<<grid, blk, 0, stream>>>(x, XH, XL, out, W1, in_map, out_map, 0,   M, chunk);
        conv_mfma<2, true><<<grid, blk, 0, stream>>>(x, XH, XL, out, W2, in_map, out_map, 64,  M, chunk);
        conv_mfma<3, true><<<grid, blk, 0, stream>>>(x, XH, XL, out, W3, in_map, out_map, 128, M, chunk);
        conv_mfma<4, true><<<grid, blk, 0, stream>>>(x, XH, XL, out, W4, in_map, out_map, 192, M, chunk);
    } else {
        conv_mfma<1, false><<<grid, blk, 0, stream>>>(x, XH, XL, out, W1, in_map, out_map, 0,   M, chunk);
        conv_mfma<2, false><<<grid, blk, 0, stream>>>(x, XH, XL, out, W2, in_map, out_map, 64,  M, chunk);
        conv_mfma<3, false><<<grid, blk, 0, stream>>>(x, XH, XL, out, W3, in_map, out_map, 128, M, chunk);
        conv_mfma<4, false><<<grid, blk, 0, stream>>>(x, XH, XL, out, W4, in_map, out_map, 192, M, chunk);
    }

    bn_stats<<<dim3(512),  dim3(256), 0, stream>>>(out, N, stats);
    bn_apply<<<dim3(2048), dim3(256), 0, stream>>>(out, N, stats, gamma, beta);
}

// Round 12
// 1697.549 us; speedup vs baseline: 1.0019x; 1.0019x over previous
//
#include <hip/hip_runtime.h>
#include <hip/hip_bf16.h>

// Sparse-conv DenseNet block via bf16x3-split MFMA (no fp32 MFMA on CDNA4).
//  - d_out [N,256] = x1|x2|x3|x4 at col offsets 0/64/128/192; later convs
//    gather previous features straight from d_out (concat is free).
//  - W[k] staged in LDS split to bf16 hi/lo in EXACT B-fragment lane order
//    WB[h][kk][t][lane][j] -> ds_read_b128 conflict-free by construction.
//  - Wave = 32 map rows/iter (2x 16-row MFMA subtiles). 3-term split product
//    (ah*bh + al*bh + ah*bl), rel err ~2^-17 (R5: absmax 0.0156, passed).
//  - R11 (= unmeasured R5-R10 change): 1024-thread blocks. conv4 (64KB LDS)
//    fits 2 blocks/CU -> 32 waves/CU (8/SIMD) vs 16. R5 profile was
//    latency-bound (Occ 41%, MfmaUtil 17%, VALU 19%, HBM 40%): double the
//    wave pool to hide ~700cy random-gather + atomic latency. VGPR=52 <= 64
//    so HW grants 8 waves/SIMD.
//  - 486 blocks <= 512 slots: one dispatch round, no straggler.
//  - Scatter via f32 global atomics; BN = stats kernel + in-place apply.
//  - Pre-committed next lever: if profile shows HBM>60% & high occupancy ->
//    CSR-inverted out_map + LDS-accumulated single-write epilogue.

typedef __attribute__((ext_vector_type(8))) short bf16x8;
typedef __attribute__((ext_vector_type(4))) float f32x4;

__device__ __forceinline__ unsigned short bfbits(float a) {
    union { __hip_bfloat16 b; unsigned short u; } cv;
    cv.b = __float2bfloat16(a);
    return cv.u;
}
__device__ __forceinline__ float bf2f(unsigned short u) {
    return __uint_as_float((unsigned)u << 16);
}
// split (a,b) -> packed hi bf16x2, lo bf16x2 (a in low half)
__device__ __forceinline__ void split2(float a, float b, unsigned& hi, unsigned& lo) {
    const unsigned short ha = bfbits(a), hb = bfbits(b);
    const float ra = a - bf2f(ha), rb = b - bf2f(hb);
    hi = (unsigned)ha | ((unsigned)hb << 16);
    lo = (unsigned)bfbits(ra) | ((unsigned)bfbits(rb) << 16);
}

#define THREADS 1024
#define BPK 18   // 18*27 = 486 blocks <= 512 co-resident slots (2/CU)

__global__ __launch_bounds__(256) void presplit_x(
    const float* __restrict__ x, unsigned* __restrict__ XH,
    unsigned* __restrict__ XL, int nvec)
{
    for (int v = blockIdx.x * 256 + threadIdx.x; v < nvec; v += gridDim.x * 256) {
        const f32x4 f = ((const f32x4*)x)[v];
        unsigned h0, l0, h1, l1;
        split2(f[0], f[1], h0, l0);
        split2(f[2], f[3], h1, l1);
        XH[v * 2] = h0; XH[v * 2 + 1] = h1;
        XL[v * 2] = l0; XL[v * 2 + 1] = l1;
    }
}

template<int SEGS, bool PSX>
__global__ __launch_bounds__(THREADS, 4) void conv_mfma(
    const float* __restrict__ x,     // [N,64] (used when !PSX)
    const short* __restrict__ XH,    // [N,64] bf16 hi (PSX)
    const short* __restrict__ XL,    // [N,64] bf16 lo (PSX)
    float* out_base,                 // d_out [N,256]: gather prev segs, scatter at col_off
    const float* __restrict__ W,     // [27][SEGS*64][64]
    const int* __restrict__ in_map,  // [27][M]
    const int* __restrict__ out_map, // [27][M]
    int col_off, int M, int chunk)
{
    constexpr int CIN = SEGS * 64;
    constexpr int NKK = CIN / 32;
    // [h][kk][t][lane][j] shorts; per (kk,t): 64 lanes x 16B, lane-ordered.
    __shared__ short WB[2 * NKK * 2048];

    const int k   = blockIdx.y;
    const int tid = threadIdx.x;

    // ---- stage W[k]: read coalesced over o, split hi/lo, write frag-order ----
    {
        const float* Wk = W + (size_t)k * CIN * 64;
        const int o = tid & 63, t = o >> 4, lr = o & 15;
        for (int c2 = (tid >> 6) * 2; c2 < CIN; c2 += 2 * (THREADS / 64)) {
            const float a = Wk[(size_t)c2 * 64 + o];
            const float b = Wk[(size_t)(c2 + 1) * 64 + o];
            unsigned hi, lo;
            split2(a, b, hi, lo);
            const int kk = c2 >> 5, kg = (c2 >> 3) & 3, j0 = c2 & 7;  // j0 even
            const int base = ((kk * 4 + t) * 64 + (kg * 16 + lr)) * 8 + j0;
            *(unsigned*)&WB[base] = hi;
            *(unsigned*)&WB[NKK * 2048 + base] = lo;
        }
    }
    __syncthreads();

    const int wave = tid >> 6, lane = tid & 63;
    const int lrow = lane & 15, kgrp = lane >> 4;
    const int cl   = kgrp * 8;            // per-lane k-offset within 32-chunk
    const int rbeg = blockIdx.x * chunk;
    const int rend = min(rbeg + chunk, M);
    const long kM  = (long)k * M;
    const short* WBl = WB + NKK * 2048;

    for (int r0 = rbeg + wave * 32; r0 < rend; r0 += (THREADS / 64) * 32) {
        f32x4 acc[2][4];
#pragma unroll
        for (int st = 0; st < 2; ++st)
#pragma unroll
            for (int t = 0; t < 4; ++t) acc[st][t] = (f32x4){0.f, 0.f, 0.f, 0.f};

        const int ir0 = in_map[kM + min(r0 + lrow,      rend - 1)];
        const int ir1 = in_map[kM + min(r0 + 16 + lrow, rend - 1)];
        const float* b0 = (const float*)out_base + (size_t)ir0 * 256;
        const float* b1 = (const float*)out_base + (size_t)ir1 * 256;

#pragma unroll 1
        for (int kk = 0; kk < NKK; ++kk) {
            const int s   = kk >> 1;
            const int off = (kk & 1) * 32 + cl;

            union { bf16x8 v; unsigned u[4]; } AH0, AL0, AH1, AL1;
            if (PSX && s == 0) {
                AH0.v = *(const bf16x8*)(XH + (size_t)ir0 * 64 + off);
                AL0.v = *(const bf16x8*)(XL + (size_t)ir0 * 64 + off);
                AH1.v = *(const bf16x8*)(XH + (size_t)ir1 * 64 + off);
                AL1.v = *(const bf16x8*)(XL + (size_t)ir1 * 64 + off);
            } else {
                const float* p0 = (s == 0) ? (x + (size_t)ir0 * 64 + off)
                                           : (b0 + (s - 1) * 64 + off);
                const float* p1 = (s == 0) ? (x + (size_t)ir1 * 64 + off)
                                           : (b1 + (s - 1) * 64 + off);
                {
                    const f32x4 f0 = *(const f32x4*)p0;
                    const f32x4 f1 = *(const f32x4*)(p0 + 4);
                    split2(f0[0], f0[1], AH0.u[0], AL0.u[0]);
                    split2(f0[2], f0[3], AH0.u[1], AL0.u[1]);
                    split2(f1[0], f1[1], AH0.u[2], AL0.u[2]);
                    split2(f1[2], f1[3], AH0.u[3], AL0.u[3]);
                }
                {
                    const f32x4 f0 = *(const f32x4*)p1;
                    const f32x4 f1 = *(const f32x4*)(p1 + 4);
                    split2(f0[0], f0[1], AH1.u[0], AL1.u[0]);
                    split2(f0[2], f0[3], AH1.u[1], AL1.u[1]);
                    split2(f1[0], f1[1], AH1.u[2], AL1.u[2]);
                    split2(f1[2], f1[3], AH1.u[3], AL1.u[3]);
                }
            }

#pragma unroll
            for (int t = 0; t < 4; ++t) {
                const int boff = ((kk * 4 + t) * 64 + lane) * 8;  // conflict-free
                const bf16x8 bh = *(const bf16x8*)&WB[boff];
                const bf16x8 bl = *(const bf16x8*)&WBl[boff];
                acc[0][t] = __builtin_amdgcn_mfma_f32_16x16x32_bf16(AH0.v, bh, acc[0][t], 0, 0, 0);
                acc[1][t] = __builtin_amdgcn_mfma_f32_16x16x32_bf16(AH1.v, bh, acc[1][t], 0, 0, 0);
                acc[0][t] = __builtin_amdgcn_mfma_f32_16x16x32_bf16(AL0.v, bh, acc[0][t], 0, 0, 0);
                acc[1][t] = __builtin_amdgcn_mfma_f32_16x16x32_bf16(AL1.v, bh, acc[1][t], 0, 0, 0);
                acc[0][t] = __builtin_amdgcn_mfma_f32_16x16x32_bf16(AH0.v, bl, acc[0][t], 0, 0, 0);
                acc[1][t] = __builtin_amdgcn_mfma_f32_16x16x32_bf16(AH1.v, bl, acc[1][t], 0, 0, 0);
            }
        }

        // ---- scatter: D row = kgrp*4+reg, col = t*16+lrow (verified layout) ----
        float* outw = out_base + col_off;
#pragma unroll
        for (int st = 0; st < 2; ++st) {
            const int rb = r0 + st * 16 + kgrp * 4;
#pragma unroll
            for (int reg = 0; reg < 4; ++reg) {
                const int rr = rb + reg;
                if (rr < rend) {
                    float* rp = outw + (size_t)out_map[kM + rr] * 256 + lrow;
                    atomicAdd(rp +  0, acc[st][0][reg]);
                    atomicAdd(rp + 16, acc[st][1][reg]);
                    atomicAdd(rp + 32, acc[st][2][reg]);
                    atomicAdd(rp + 48, acc[st][3][reg]);
                }
            }
        }
    }
}

__global__ __launch_bounds__(256) void bn_stats(
    const float* __restrict__ y, int N, float* __restrict__ stats /*[512]*/)
{
    const int c = threadIdx.x;
    float s = 0.f, s2 = 0.f;
    for (int n = blockIdx.x; n < N; n += gridDim.x) {
        const float v = y[(size_t)n * 256 + c];
        s += v;
        s2 += v * v;
    }
    atomicAdd(&stats[c], s);
    atomicAdd(&stats[256 + c], s2);
}

__global__ __launch_bounds__(256) void bn_apply(
    float* __restrict__ y, int N, const float* __restrict__ stats,
    const float* __restrict__ gamma, const float* __restrict__ beta)
{
    const int c = threadIdx.x;
    const float invN = 1.0f / (float)N;
    const float mean = stats[c] * invN;
    const float var  = stats[256 + c] * invN - mean * mean;
    const float scale = (1.0f / sqrtf(var + 1e-5f)) * gamma[c];
    const float shift = beta[c] - mean * scale;
    for (int n = blockIdx.x; n < N; n += gridDim.x) {
        const size_t idx = (size_t)n * 256 + c;
        y[idx] = y[idx] * scale + shift;
    }
}

extern "C" void kernel_launch(void* const* d_in, const int* in_sizes, int n_in,
                              void* d_out, int out_size, void* d_ws, size_t ws_size,
                              hipStream_t stream) {
    const float* x     = (const float*)d_in[0];
    const float* W1    = (const float*)d_in[1];
    const float* W2    = (const float*)d_in[2];
    const float* W3    = (const float*)d_in[3];
    const float* W4    = (const float*)d_in[4];
    const float* gamma = (const float*)d_in[5];
    const float* beta  = (const float*)d_in[6];
    const int* in_map  = (const int*)d_in[7];
    const int* out_map = (const int*)d_in[8];

    const int N = in_sizes[0] / 64;       // 120000
    const int M = in_sizes[7] / 27;       // 60000
    float* out   = (float*)d_out;         // [N,256]
    float* stats = (float*)d_ws;          // 512 floats at ws base

    // ws layout: [0,2KB) stats | [4KB,..) XH [N*64 bf16] | XL [N*64 bf16]
    short* XH = (short*)((char*)d_ws + 4096);
    short* XL = XH + (size_t)N * 64;
    const size_t ws_need = 4096 + (size_t)N * 64 * 2 * 2;
    const bool psx = (ws_size >= ws_need);

    hipMemsetAsync(d_out, 0, (size_t)N * 256 * sizeof(float), stream);
    hipMemsetAsync(d_ws, 0, 2048, stream);

    const int chunk = ((((M + BPK - 1) / BPK) + 31) & ~31);  // 3360
    const int gx = (M + chunk - 1) / chunk;                  // 18
    dim3 blk(THREADS);
    dim3 grid(gx, 27);

    if (psx) {
        presplit_x<<<dim3(1024), dim3(256), 0, stream>>>(x, (unsigned*)XH, (unsigned*)XL, N * 16);
        conv_mfma<1, true><<<grid, blk, 0, stream>>>(x, XH, XL, out, W1, in_map, out_map, 0,   M, chunk);
        conv_mfma<2, true><<<grid, blk, 0, stream>>>(x, XH, XL, out, W2, in_map, out_map, 64,  M, chunk);
        conv_mfma<3, true><<<grid, blk, 0, stream>>>(x, XH, XL, out, W3, in_map, out_map, 128, M, chunk);
        conv_mfma<4, true><<<grid, blk, 0, stream>>>(x, XH, XL, out, W4, in_map, out_map, 192, M, chunk);
    } else {
        conv_mfma<1, false><<<grid, blk, 0, stream>>>(x, XH, XL, out, W1, in_map, out_map, 0,   M, chunk);
        conv_mfma<2, false><<<grid, blk, 0, stream>>>(x, XH, XL, out, W2, in_map, out_map, 64,  M, chunk);
        conv_mfma<3, false><<<grid, blk, 0, stream>>>(x, XH, XL, out, W3, in_map, out_map, 128, M, chunk);
        conv_mfma<4, false><<<grid, blk, 0, stream>>>(x, XH, XL, out, W4, in_map, out_map, 192, M, chunk);
    }

    bn_stats<<<dim3(512),  dim3(256), 0, stream>>>(out, N, stats);
    bn_apply<<<dim3(2048), dim3(256), 0, stream>>>(out, N, stats, gamma, beta);
}